// Round 3
// baseline (315.968 us; speedup 1.0000x reference)
//
#include <hip/hip_runtime.h>
#include <hip/hip_bf16.h>
#include <stdint.h>

// Problem constants (fixed by the reference)
#define NS   8192
#define XD   512
#define HD   2048
#define YD   512

typedef unsigned short u16;
using bf16x8 = __attribute__((ext_vector_type(8))) short;
using f32x4  = __attribute__((ext_vector_type(4))) float;

__device__ __forceinline__ float bf2f(u16 u) {
  union { uint32_t i; float f; } v; v.i = ((uint32_t)u) << 16; return v.f;
}
// dtype-adaptive element load: f32 flag ? read float : read bf16
__device__ __forceinline__ float ld_in(const void* p, int f32, size_t i) {
  return f32 ? ((const float*)p)[i] : bf2f(((const u16*)p)[i]);
}

// ---------------- dtype detection ----------------
// Genuine bf16 inputs here are bounded (|v| <~ 6). fp32 bits read as bf16
// contain wild exponents / NaNs w.h.p. Probe first min(n, 8192) u16s
// (always within the buffer under either dtype).
struct Args10 { const void* p[10]; int n[10]; };

__global__ void detect_kernel(Args10 a, int* __restrict__ flags) {
  const int b = blockIdx.x;
  const u16* q = (const u16*)a.p[b];
  int m = a.n[b]; if (m > 8192) m = 8192;
  int wild = 0;
  for (int i = threadIdx.x; i < m; i += blockDim.x) {
    float v = bf2f(q[i]);
    if (!(fabsf(v) <= 1000.0f)) wild = 1;   // catches huge AND NaN
  }
  if (wild) atomicOr(&flags[b], 1);
}

// ---------------- input normalization ----------------
__global__ __launch_bounds__(256) void conv_bf16_kernel(const void* __restrict__ src,
                                                        const int* __restrict__ flags, int fidx,
                                                        u16* __restrict__ dst, int n) {
  const int f = flags[fidx];
  for (int i = blockIdx.x * blockDim.x + threadIdx.x; i < n; i += gridDim.x * blockDim.x) {
    if (f) {
      __hip_bfloat16 hb = __float2bfloat16(((const float*)src)[i]);
      dst[i] = *(const u16*)&hb;
    } else {
      dst[i] = ((const u16*)src)[i];
    }
  }
}

// all four biases -> one fp32 array [b1mu(2048) | b2mu(512) | b1lv(2048) | b2lv(512)]
__global__ __launch_bounds__(256) void conv_bias_kernel(const void* b1m, const void* b2m,
                                                        const void* b1l, const void* b2l,
                                                        const int* __restrict__ flags,
                                                        float* __restrict__ o) {
  int i = blockIdx.x * blockDim.x + threadIdx.x;   // 5120 total
  if (i < 2048)      o[i] = ld_in(b1m, flags[3], i);
  else if (i < 2560) o[i] = ld_in(b2m, flags[5], i - 2048);
  else if (i < 4608) o[i] = ld_in(b1l, flags[7], i - 2560);
  else if (i < 5120) o[i] = ld_in(b2l, flags[9], i - 4608);
}

// adaptive transpose: in [R,C] (bf16 or f32 per flag) -> out [C,R] bf16
__global__ __launch_bounds__(256) void transpose_adp(const void* __restrict__ in,
                                                     const int* __restrict__ flags, int fidx,
                                                     u16* __restrict__ out, int R, int C) {
  __shared__ u16 tile[32][33];
  const int f = flags[fidx];
  int c0 = blockIdx.x * 32, r0 = blockIdx.y * 32;
  int tx = threadIdx.x, ty = threadIdx.y;
  for (int i = ty; i < 32; i += 8) {
    __hip_bfloat16 hb = __float2bfloat16(ld_in(in, f, (size_t)(r0 + i) * C + (c0 + tx)));
    tile[i][tx] = *(const u16*)&hb;
  }
  __syncthreads();
  for (int i = ty; i < 32; i += 8)
    out[(size_t)(c0 + i) * R + (r0 + tx)] = tile[tx][i];
}

// ---------------- y column stats ----------------
__global__ __launch_bounds__(256) void ystats_kernel(const void* __restrict__ y,
                                                     const int* __restrict__ flags,
                                                     float* __restrict__ Sy,
                                                     float* __restrict__ Sy2) {
  const int f = flags[1];
  const int t = threadIdx.x;
  const int r0 = blockIdx.x * 128;
  float s0 = 0.f, s1 = 0.f, q0 = 0.f, q1 = 0.f;
  for (int r = r0; r < r0 + 128; ++r) {
    float a = ld_in(y, f, (size_t)r * YD + t);
    float b = ld_in(y, f, (size_t)r * YD + t + 256);
    s0 += a; q0 += a * a;
    s1 += b; q1 += b * b;
  }
  atomicAdd(&Sy[t], s0);        atomicAdd(&Sy2[t], q0);
  atomicAdd(&Sy[t + 256], s1);  atomicAdd(&Sy2[t + 256], q1);
}

// ---------------- GEMM (m97 structure) ----------------
// MODE 0: relu(v)+bias -> bf16 C     (GEMM1, h)
// MODE 1: v+bias       -> f32 C      (GEMM2 mu head)
// MODE 2: loss epilogue, no C store  (GEMM2 lv head: lvp stays in registers)
template <int MODE>
__global__ __launch_bounds__(256) void gemm_bt(
    const u16* __restrict__ A,      // [M,K] bf16
    const u16* __restrict__ Bt,     // [N,K] bf16
    const float* __restrict__ bias, // [N]   f32
    void* __restrict__ C, int M, int N, int K,
    const void* __restrict__ y, const int* __restrict__ flags,
    const float* __restrict__ mu, const float* __restrict__ Sy,
    const float* __restrict__ Sy2, double* __restrict__ gacc) {
  __shared__ alignas(16) u16 As[128 * 32];
  __shared__ alignas(16) u16 Bs[128 * 32];

  const int tid  = threadIdx.x;
  const int wid  = tid >> 6;
  const int lane = tid & 63;
  const int bm0  = blockIdx.y * 128;
  const int bn0  = blockIdx.x * 128;

  const int mrow = (wid >> 1) * 64;
  const int ncol = (wid & 1) * 64;
  const int quad = lane >> 4;
  const int c16  = lane & 15;
  const int koff = quad * 8;

  const int srow = lane >> 2;
  const int scol = (lane & 3) * 8;

  f32x4 acc[4][4] = {};

  for (int k0 = 0; k0 < K; k0 += 32) {
#pragma unroll
    for (int j = 0; j < 2; ++j) {
      const int grp = wid * 2 + j;
      const int row = grp * 16 + srow;
      const u16* ag = A  + (size_t)(bm0 + row) * K + (k0 + scol);
      const u16* bg = Bt + (size_t)(bn0 + row) * K + (k0 + scol);
      __builtin_amdgcn_global_load_lds(
          (__attribute__((address_space(1))) void*)ag,
          (__attribute__((address_space(3))) void*)(As + grp * 512), 16, 0, 0);
      __builtin_amdgcn_global_load_lds(
          (__attribute__((address_space(1))) void*)bg,
          (__attribute__((address_space(3))) void*)(Bs + grp * 512), 16, 0, 0);
    }
    __syncthreads();

    bf16x8 af[4], bfr[4];
#pragma unroll
    for (int mi = 0; mi < 4; ++mi)
      af[mi] = *(const bf16x8*)&As[(mrow + mi * 16 + c16) * 32 + koff];
#pragma unroll
    for (int ni = 0; ni < 4; ++ni)
      bfr[ni] = *(const bf16x8*)&Bs[(ncol + ni * 16 + c16) * 32 + koff];

#pragma unroll
    for (int mi = 0; mi < 4; ++mi)
#pragma unroll
      for (int ni = 0; ni < 4; ++ni)
        acc[mi][ni] = __builtin_amdgcn_mfma_f32_16x16x32_bf16(
            af[mi], bfr[ni], acc[mi][ni], 0, 0, 0);
    __syncthreads();
  }

  // Epilogue. C/D layout (m89): col = lane&15, row = quad*4 + reg.
  if constexpr (MODE == 2) {
    const int yf = flags[1];
    const float invN = 1.0f / (float)NS;
    float s = 0.f;
#pragma unroll
    for (int ni = 0; ni < 4; ++ni) {
      const int gcol = bn0 + ncol + ni * 16 + c16;
      const float bv = bias[gcol], syv = Sy[gcol], sy2v = Sy2[gcol];
#pragma unroll
      for (int mi = 0; mi < 4; ++mi) {
#pragma unroll
        for (int r = 0; r < 4; ++r) {
          const int grow = bm0 + mrow + mi * 16 + quad * 4 + r;
          const float lvp = acc[mi][ni][r] + bv;
          const float lv = tanhf(lvp);
          const float w  = 0.5f * expf(-lv);
          const size_t ix = (size_t)grow * YD + gcol;
          const float m  = mu[ix];
          const float yv = ld_in(y, yf, ix);
          s += w * (yv * yv - 2.f * m * yv + (2.f * m * syv - sy2v) * invN);
        }
      }
    }
    for (int off = 32; off > 0; off >>= 1) s += __shfl_down(s, off);
    __shared__ double bs[4];
    if (lane == 0) bs[wid] = (double)s;
    __syncthreads();
    if (tid == 0) atomicAdd(gacc, bs[0] + bs[1] + bs[2] + bs[3]);
  } else {
#pragma unroll
    for (int ni = 0; ni < 4; ++ni) {
      const int gcol = bn0 + ncol + ni * 16 + c16;
      const float bv = bias[gcol];
#pragma unroll
      for (int mi = 0; mi < 4; ++mi) {
#pragma unroll
        for (int r = 0; r < 4; ++r) {
          const int grow = bm0 + mrow + mi * 16 + quad * 4 + r;
          float v = acc[mi][ni][r] + bv;
          if constexpr (MODE == 0)
            ((__hip_bfloat16*)C)[(size_t)grow * N + gcol] = __float2bfloat16(fmaxf(v, 0.f));
          else
            ((float*)C)[(size_t)grow * N + gcol] = v;
        }
      }
    }
  }
}

// Output is the reference's fp32 scalar (round-2 evidence: fp32 NaN propagated
// through the harness readback verbatim) -> store float.
__global__ void finalize_kernel(const double* __restrict__ gacc,
                                float* __restrict__ out) {
  if (threadIdx.x == 0)
    out[0] = (float)(-gacc[0] / (double)NS);
}

// ---------------- launch ----------------
extern "C" void kernel_launch(void* const* d_in, const int* in_sizes, int n_in,
                              void* d_out, int out_size, void* d_ws, size_t ws_size,
                              hipStream_t stream) {
  char* ws = (char*)d_ws;
  double* gacc = (double*)ws;                    // [0,8)
  int*    flags = (int*)(ws + 16);               // [16,80)
  float*  Sy    = (float*)(ws + 128);            // 512 f32
  float*  Sy2   = (float*)(ws + 2176);           // 512 f32
  float*  biasv = (float*)(ws + 4224);           // 5120 f32 -> ends 24704
  u16* xb   = (u16*)(ws + 24704);                // [NS,XD] bf16, 8 MB
  u16* W1tm = xb + (size_t)NS * XD;              // [HD,XD] 2 MB
  u16* W2tm = W1tm + (size_t)HD * XD;            // [YD,HD] 2 MB
  u16* W1tl = W2tm + (size_t)YD * HD;            // 2 MB
  u16* W2tl = W1tl + (size_t)HD * XD;            // 2 MB
  u16* h    = W2tl + (size_t)YD * HD;            // [NS,HD] bf16, 32 MB
  float* mu = (float*)(h + (size_t)NS * HD);     // [NS,YD] f32, 16 MB  (total ~64 MB)

  hipMemsetAsync(d_ws, 0, 4224, stream);         // acc + flags + Sy + Sy2

  Args10 a;
  for (int i = 0; i < 10; ++i) { a.p[i] = d_in[i]; a.n[i] = in_sizes[i]; }
  detect_kernel<<<10, 256, 0, stream>>>(a, flags);

  conv_bf16_kernel<<<4096, 256, 0, stream>>>(d_in[0], flags, 0, xb, NS * XD);
  conv_bias_kernel<<<20, 256, 0, stream>>>(d_in[3], d_in[5], d_in[7], d_in[9], flags, biasv);

  dim3 tb(32, 8);
  transpose_adp<<<dim3(HD / 32, XD / 32), tb, 0, stream>>>(d_in[2], flags, 2, W1tm, XD, HD);
  transpose_adp<<<dim3(YD / 32, HD / 32), tb, 0, stream>>>(d_in[4], flags, 4, W2tm, HD, YD);
  transpose_adp<<<dim3(HD / 32, XD / 32), tb, 0, stream>>>(d_in[6], flags, 6, W1tl, XD, HD);
  transpose_adp<<<dim3(YD / 32, HD / 32), tb, 0, stream>>>(d_in[8], flags, 8, W2tl, HD, YD);

  ystats_kernel<<<64, 256, 0, stream>>>(d_in[1], flags, Sy, Sy2);

  const float* b1m = biasv, *b2m = biasv + 2048, *b1l = biasv + 2560, *b2l = biasv + 4608;

  // mu head
  gemm_bt<0><<<dim3(HD / 128, NS / 128), 256, 0, stream>>>(
      xb, W1tm, b1m, h, NS, HD, XD, nullptr, flags, nullptr, nullptr, nullptr, nullptr);
  gemm_bt<1><<<dim3(YD / 128, NS / 128), 256, 0, stream>>>(
      h, W2tm, b2m, mu, NS, YD, HD, nullptr, flags, nullptr, nullptr, nullptr, nullptr);
  // lv head (reuse h); loss fused into GEMM2 epilogue
  gemm_bt<0><<<dim3(HD / 128, NS / 128), 256, 0, stream>>>(
      xb, W1tl, b1l, h, NS, HD, XD, nullptr, flags, nullptr, nullptr, nullptr, nullptr);
  gemm_bt<2><<<dim3(YD / 128, NS / 128), 256, 0, stream>>>(
      h, W2tl, b2l, nullptr, NS, YD, HD, d_in[1], flags, mu, Sy, Sy2, gacc);

  finalize_kernel<<<1, 64, 0, stream>>>(gacc, (float*)d_out);
}

// Round 4
// 285.446 us; speedup vs baseline: 1.1069x; 1.1069x over previous
//
#include <hip/hip_runtime.h>
#include <hip/hip_bf16.h>
#include <stdint.h>

// Problem constants (fixed by the reference)
#define NS   8192
#define XD   512
#define HD   2048
#define YD   512

typedef unsigned short u16;
using bf16x8 = __attribute__((ext_vector_type(8))) short;
using f32x4  = __attribute__((ext_vector_type(4))) float;

__device__ __forceinline__ float bf2f(u16 u) {
  union { uint32_t i; float f; } v; v.i = ((uint32_t)u) << 16; return v.f;
}
__device__ __forceinline__ u16 f2b(float f) {
  __hip_bfloat16 hb = __float2bfloat16(f);
  return *(const u16*)&hb;
}
// dtype-adaptive element load: f32 flag ? read float : read bf16
__device__ __forceinline__ float ld_in(const void* p, int f32, size_t i) {
  return f32 ? ((const float*)p)[i] : bf2f(((const u16*)p)[i]);
}

// ---------------- dtype detection (round-2/3 lesson: inputs are MIXED dtype;
// detect on-device: fp32 bits read as bf16 contain wild exponents/NaN w.h.p.)
struct Args10 { const void* p[10]; int n[10]; };

__global__ void detect_kernel(Args10 a, int* __restrict__ flags) {
  const int b = blockIdx.x;
  const u16* q = (const u16*)a.p[b];
  int m = a.n[b]; if (m > 8192) m = 8192;
  int wild = 0;
  for (int i = threadIdx.x; i < m; i += blockDim.x) {
    float v = bf2f(q[i]);
    if (!(fabsf(v) <= 1000.0f)) wild = 1;   // catches huge AND NaN
  }
  if (wild) atomicOr(&flags[b], 1);
}

// ---------------- fused prep: x->bf16 copy, biases->f32, y column stats ----
__global__ __launch_bounds__(256) void prep_kernel(
    const void* __restrict__ x, const void* __restrict__ y,
    const void* b1m, const void* b2m, const void* b1l, const void* b2l,
    const int* __restrict__ flags,
    u16* __restrict__ xb, float* __restrict__ biasv,
    float* __restrict__ Sy, float* __restrict__ Sy2) {
  const int b = blockIdx.x;
  if (b < 2048) {                      // x conversion: 8 elems/thread
    const int f = flags[0];
    const size_t base = (size_t)b * 2048 + (size_t)threadIdx.x * 8;
    alignas(16) u16 o[8];
    if (f) {
      const float4* s = (const float4*)((const float*)x + base);
      float4 v0 = s[0], v1 = s[1];
      o[0]=f2b(v0.x); o[1]=f2b(v0.y); o[2]=f2b(v0.z); o[3]=f2b(v0.w);
      o[4]=f2b(v1.x); o[5]=f2b(v1.y); o[6]=f2b(v1.z); o[7]=f2b(v1.w);
    } else {
      *(uint4*)o = *(const uint4*)((const u16*)x + base);
    }
    *(uint4*)(xb + base) = *(const uint4*)o;
  } else if (b < 2112) {               // y column stats (64 blocks x 128 rows)
    const int f = flags[1];
    const int t = threadIdx.x;
    const int r0 = (b - 2048) * 128;
    float s0 = 0.f, s1 = 0.f, q0 = 0.f, q1 = 0.f;
    for (int r = r0; r < r0 + 128; ++r) {
      float a = ld_in(y, f, (size_t)r * YD + t);
      float c = ld_in(y, f, (size_t)r * YD + t + 256);
      s0 += a; q0 += a * a;
      s1 += c; q1 += c * c;
    }
    atomicAdd(&Sy[t], s0);        atomicAdd(&Sy2[t], q0);
    atomicAdd(&Sy[t + 256], s1);  atomicAdd(&Sy2[t + 256], q1);
  } else {                             // biases -> [b1m(2048)|b2m(512)|b1l(2048)|b2l(512)]
    for (int i = threadIdx.x; i < 5120; i += 256) {
      float v;
      if (i < 2048)      v = ld_in(b1m, flags[3], i);
      else if (i < 2560) v = ld_in(b2m, flags[5], i - 2048);
      else if (i < 4608) v = ld_in(b1l, flags[7], i - 2560);
      else               v = ld_in(b2l, flags[9], i - 4608);
      biasv[i] = v;
    }
  }
}

// ---------------- all 4 weight transposes in one launch --------------------
// in [R,C] (bf16 or f32 per flag) -> out [C,R] bf16; 32x32 tiles, 4096 blocks.
__global__ __launch_bounds__(256) void transpose_all(
    const void* w1m, const void* w2m, const void* w1l, const void* w2l,
    const int* __restrict__ flags,
    u16* o1m, u16* o2m, u16* o1l, u16* o2l) {
  __shared__ u16 tile[32][33];
  const int id = blockIdx.x, which = id >> 10, t = id & 1023;
  const void* in; u16* out; int R, C, fidx;
  if (which == 0)      { in = w1m; out = o1m; R = XD; C = HD; fidx = 2; }
  else if (which == 1) { in = w2m; out = o2m; R = HD; C = YD; fidx = 4; }
  else if (which == 2) { in = w1l; out = o1l; R = XD; C = HD; fidx = 6; }
  else                 { in = w2l; out = o2l; R = HD; C = YD; fidx = 8; }
  const int f = flags[fidx];
  const int nbx = C >> 5;
  const int bx = t % nbx, by = t / nbx;
  const int c0 = bx * 32, r0 = by * 32;
  const int tx = threadIdx.x & 31, ty = threadIdx.x >> 5;
  for (int i = ty; i < 32; i += 8)
    tile[i][tx] = f2b(ld_in(in, f, (size_t)(r0 + i) * C + (c0 + tx)));
  __syncthreads();
  for (int i = ty; i < 32; i += 8)
    out[(size_t)(c0 + i) * R + (r0 + tx)] = tile[tx][i];
}

// ---------------- GEMM (m97 structure, BK=64, XOR-swizzled LDS) ------------
// C[M,N] = act(A[M,K] @ Bt[N,K]^T + bias[N])
// BK=64: halves barrier-drain count vs BK=32 (K=512 -> 8 iters). LDS rows are
// 128 B -> every row would alias the same banks, so stage global k-chunk
// (sc ^ srow) at LDS chunk sc; fragment reads use chunk (q ^ (row&7)).
// Staging now covers full 128-B rows (whole cache lines, vs 64-B before).
// MODE 0: relu(v+bias) -> bf16 C   (GEMM1 -> h)
// MODE 1: v+bias       -> f32 C    (GEMM2 mu head)
// MODE 2: loss epilogue, no C store (GEMM2 lv head)
template <int MODE>
__global__ __launch_bounds__(256) void gemm_bt(
    const u16* __restrict__ A,      // [M,K] bf16
    const u16* __restrict__ Bt,     // [N,K] bf16
    const float* __restrict__ bias, // [N]   f32
    void* __restrict__ C, int M, int N, int K,
    const void* __restrict__ y, const int* __restrict__ flags,
    const float* __restrict__ mu, const float* __restrict__ Sy,
    const float* __restrict__ Sy2, double* __restrict__ gacc) {
  __shared__ alignas(16) u16 As[128 * 64];   // 16 KB
  __shared__ alignas(16) u16 Bs[128 * 64];   // 16 KB

  const int tid  = threadIdx.x;
  const int wid  = tid >> 6;
  const int lane = tid & 63;
  const int bm0  = blockIdx.y * 128;
  const int bn0  = blockIdx.x * 128;

  const int mrow = (wid >> 1) * 64;
  const int ncol = (wid & 1) * 64;
  const int quad = lane >> 4;
  const int c16  = lane & 15;
  const int cswz = c16 & 7;           // row-derived XOR key for fragment reads

  const int srow = lane >> 3;         // 0..7: row within 8-row staging group
  const int sc   = lane & 7;          // 0..7: 16-B chunk within 128-B row
  const int scg  = (sc ^ srow) * 8;   // swizzled global k element offset

  f32x4 acc[4][4] = {};

  for (int k0 = 0; k0 < K; k0 += 64) {
#pragma unroll
    for (int j = 0; j < 4; ++j) {     // wave wid stages rows [wid*32, wid*32+32)
      const int row = wid * 32 + j * 8 + srow;
      const u16* ag = A  + (size_t)(bm0 + row) * K + (k0 + scg);
      const u16* bg = Bt + (size_t)(bn0 + row) * K + (k0 + scg);
      __builtin_amdgcn_global_load_lds(
          (__attribute__((address_space(1))) void*)ag,
          (__attribute__((address_space(3))) void*)(As + (wid * 32 + j * 8) * 64), 16, 0, 0);
      __builtin_amdgcn_global_load_lds(
          (__attribute__((address_space(1))) void*)bg,
          (__attribute__((address_space(3))) void*)(Bs + (wid * 32 + j * 8) * 64), 16, 0, 0);
    }
    __syncthreads();

#pragma unroll
    for (int h = 0; h < 2; ++h) {     // two K=32 MFMA steps per BK=64 tile
      const int q = h * 4 + quad;     // global k-chunk wanted
      bf16x8 af[4], bfr[4];
#pragma unroll
      for (int mi = 0; mi < 4; ++mi) {
        const int rl = mrow + mi * 16 + c16;
        af[mi] = *(const bf16x8*)&As[rl * 64 + ((q ^ cswz) * 8)];
      }
#pragma unroll
      for (int ni = 0; ni < 4; ++ni) {
        const int rl = ncol + ni * 16 + c16;
        bfr[ni] = *(const bf16x8*)&Bs[rl * 64 + ((q ^ cswz) * 8)];
      }
#pragma unroll
      for (int mi = 0; mi < 4; ++mi)
#pragma unroll
        for (int ni = 0; ni < 4; ++ni)
          acc[mi][ni] = __builtin_amdgcn_mfma_f32_16x16x32_bf16(
              af[mi], bfr[ni], acc[mi][ni], 0, 0, 0);
    }
    __syncthreads();
  }

  // Epilogue. C/D layout (m89): col = lane&15, row = quad*4 + reg.
  if constexpr (MODE == 2) {
    const int yf = flags[1];
    const float invN = 1.0f / (float)NS;
    float s = 0.f;
#pragma unroll
    for (int ni = 0; ni < 4; ++ni) {
      const int gcol = bn0 + ncol + ni * 16 + c16;
      const float bv = bias[gcol], syv = Sy[gcol], sy2v = Sy2[gcol];
#pragma unroll
      for (int mi = 0; mi < 4; ++mi) {
#pragma unroll
        for (int r = 0; r < 4; ++r) {
          const int grow = bm0 + mrow + mi * 16 + quad * 4 + r;
          const float lvp = acc[mi][ni][r] + bv;
          const float lv = tanhf(lvp);
          const float w  = 0.5f * expf(-lv);
          const size_t ix = (size_t)grow * YD + gcol;
          const float m  = mu[ix];
          const float yv = ld_in(y, yf, ix);
          s += w * (yv * yv - 2.f * m * yv + (2.f * m * syv - sy2v) * invN);
        }
      }
    }
    for (int off = 32; off > 0; off >>= 1) s += __shfl_down(s, off);
    __shared__ double bs[4];
    if (lane == 0) bs[wid] = (double)s;
    __syncthreads();
    if (tid == 0) atomicAdd(gacc, bs[0] + bs[1] + bs[2] + bs[3]);
  } else {
#pragma unroll
    for (int ni = 0; ni < 4; ++ni) {
      const int gcol = bn0 + ncol + ni * 16 + c16;
      const float bv = bias[gcol];
#pragma unroll
      for (int mi = 0; mi < 4; ++mi) {
#pragma unroll
        for (int r = 0; r < 4; ++r) {
          const int grow = bm0 + mrow + mi * 16 + quad * 4 + r;
          float v = acc[mi][ni][r] + bv;
          if constexpr (MODE == 0)
            ((__hip_bfloat16*)C)[(size_t)grow * N + gcol] = __float2bfloat16(fmaxf(v, 0.f));
          else
            ((float*)C)[(size_t)grow * N + gcol] = v;
        }
      }
    }
  }
}

// Output is the reference's fp32 scalar (round-2 evidence) -> store float.
__global__ void finalize_kernel(const double* __restrict__ gacc,
                                float* __restrict__ out) {
  if (threadIdx.x == 0)
    out[0] = (float)(-gacc[0] / (double)NS);
}

// ---------------- launch ----------------
extern "C" void kernel_launch(void* const* d_in, const int* in_sizes, int n_in,
                              void* d_out, int out_size, void* d_ws, size_t ws_size,
                              hipStream_t stream) {
  char* ws = (char*)d_ws;
  double* gacc = (double*)ws;                    // [0,8)
  int*    flags = (int*)(ws + 16);               // [16,80)
  float*  Sy    = (float*)(ws + 128);            // 512 f32
  float*  Sy2   = (float*)(ws + 2176);           // 512 f32
  float*  biasv = (float*)(ws + 4224);           // 5120 f32 -> ends 24704
  u16* xb   = (u16*)(ws + 24704);                // [NS,XD] bf16, 8 MB
  u16* W1tm = xb + (size_t)NS * XD;              // [HD,XD] 2 MB
  u16* W2tm = W1tm + (size_t)HD * XD;            // [YD,HD] 2 MB
  u16* W1tl = W2tm + (size_t)YD * HD;            // 2 MB
  u16* W2tl = W1tl + (size_t)HD * XD;            // 2 MB
  u16* h    = W2tl + (size_t)YD * HD;            // [NS,HD] bf16, 32 MB
  float* mu = (float*)(h + (size_t)NS * HD);     // [NS,YD] f32, 16 MB (~62 MB total)

  hipMemsetAsync(d_ws, 0, 4224, stream);         // gacc + flags + Sy + Sy2

  Args10 a;
  for (int i = 0; i < 10; ++i) { a.p[i] = d_in[i]; a.n[i] = in_sizes[i]; }
  detect_kernel<<<10, 256, 0, stream>>>(a, flags);

  prep_kernel<<<2113, 256, 0, stream>>>(d_in[0], d_in[1], d_in[3], d_in[5],
                                        d_in[7], d_in[9], flags, xb, biasv, Sy, Sy2);
  transpose_all<<<4096, 256, 0, stream>>>(d_in[2], d_in[4], d_in[6], d_in[8],
                                          flags, W1tm, W2tm, W1tl, W2tl);

  const float* b1m = biasv, *b2m = biasv + 2048, *b1l = biasv + 2560, *b2l = biasv + 4608;

  // mu head
  gemm_bt<0><<<dim3(HD / 128, NS / 128), 256, 0, stream>>>(
      xb, W1tm, b1m, h, NS, HD, XD, nullptr, flags, nullptr, nullptr, nullptr, nullptr);
  gemm_bt<1><<<dim3(YD / 128, NS / 128), 256, 0, stream>>>(
      h, W2tm, b2m, mu, NS, YD, HD, nullptr, flags, nullptr, nullptr, nullptr, nullptr);
  // lv head (reuse h); loss fused into GEMM2 epilogue
  gemm_bt<0><<<dim3(HD / 128, NS / 128), 256, 0, stream>>>(
      xb, W1tl, b1l, h, NS, HD, XD, nullptr, flags, nullptr, nullptr, nullptr, nullptr);
  gemm_bt<2><<<dim3(YD / 128, NS / 128), 256, 0, stream>>>(
      h, W2tl, b2l, nullptr, NS, YD, HD, d_in[1], flags, mu, Sy, Sy2, gacc);

  finalize_kernel<<<1, 64, 0, stream>>>(gacc, (float*)d_out);
}

// Round 5
// 250.440 us; speedup vs baseline: 1.2617x; 1.1398x over previous
//
#include <hip/hip_runtime.h>
#include <hip/hip_bf16.h>
#include <stdint.h>

// Problem constants (fixed by the reference)
#define NS   8192
#define XD   512
#define HD   2048
#define YD   512

typedef unsigned short u16;
using bf16x8 = __attribute__((ext_vector_type(8))) short;
using f32x4  = __attribute__((ext_vector_type(4))) float;

__device__ __forceinline__ float bf2f(u16 u) {
  union { uint32_t i; float f; } v; v.i = ((uint32_t)u) << 16; return v.f;
}
__device__ __forceinline__ u16 f2b(float f) {
  __hip_bfloat16 hb = __float2bfloat16(f);
  return *(const u16*)&hb;
}
// dtype-adaptive element load: f32 flag ? read float : read bf16
__device__ __forceinline__ float ld_in(const void* p, int f32, size_t i) {
  return f32 ? ((const float*)p)[i] : bf2f(((const u16*)p)[i]);
}

// ---------------- dtype detection (round-2/3 lesson: inputs are MIXED dtype;
// detect on-device: fp32 bits read as bf16 contain wild exponents/NaN w.h.p.)
struct Args10 { const void* p[10]; int n[10]; };

__global__ void detect_kernel(Args10 a, int* __restrict__ flags) {
  const int b = blockIdx.x;
  const u16* q = (const u16*)a.p[b];
  int m = a.n[b]; if (m > 8192) m = 8192;
  int wild = 0;
  for (int i = threadIdx.x; i < m; i += blockDim.x) {
    float v = bf2f(q[i]);
    if (!(fabsf(v) <= 1000.0f)) wild = 1;   // catches huge AND NaN
  }
  if (wild) atomicOr(&flags[b], 1);
}

// ---------------- fused prep: x->bf16 copy, biases->f32, y column stats ----
__global__ __launch_bounds__(256) void prep_kernel(
    const void* __restrict__ x, const void* __restrict__ y,
    const void* b1m, const void* b2m, const void* b1l, const void* b2l,
    const int* __restrict__ flags,
    u16* __restrict__ xb, float* __restrict__ biasv,
    float* __restrict__ Sy, float* __restrict__ Sy2) {
  const int b = blockIdx.x;
  if (b < 2048) {                      // x conversion: 8 elems/thread
    const int f = flags[0];
    const size_t base = (size_t)b * 2048 + (size_t)threadIdx.x * 8;
    alignas(16) u16 o[8];
    if (f) {
      const float4* s = (const float4*)((const float*)x + base);
      float4 v0 = s[0], v1 = s[1];
      o[0]=f2b(v0.x); o[1]=f2b(v0.y); o[2]=f2b(v0.z); o[3]=f2b(v0.w);
      o[4]=f2b(v1.x); o[5]=f2b(v1.y); o[6]=f2b(v1.z); o[7]=f2b(v1.w);
    } else {
      *(uint4*)o = *(const uint4*)((const u16*)x + base);
    }
    *(uint4*)(xb + base) = *(const uint4*)o;
  } else if (b < 2112) {               // y column stats (64 blocks x 128 rows)
    const int f = flags[1];
    const int t = threadIdx.x;
    const int r0 = (b - 2048) * 128;
    float s0 = 0.f, s1 = 0.f, q0 = 0.f, q1 = 0.f;
    for (int r = r0; r < r0 + 128; ++r) {
      float a = ld_in(y, f, (size_t)r * YD + t);
      float c = ld_in(y, f, (size_t)r * YD + t + 256);
      s0 += a; q0 += a * a;
      s1 += c; q1 += c * c;
    }
    atomicAdd(&Sy[t], s0);        atomicAdd(&Sy2[t], q0);
    atomicAdd(&Sy[t + 256], s1);  atomicAdd(&Sy2[t + 256], q1);
  } else {                             // biases -> [b1m(2048)|b2m(512)|b1l(2048)|b2l(512)]
    for (int i = threadIdx.x; i < 5120; i += 256) {
      float v;
      if (i < 2048)      v = ld_in(b1m, flags[3], i);
      else if (i < 2560) v = ld_in(b2m, flags[5], i - 2048);
      else if (i < 4608) v = ld_in(b1l, flags[7], i - 2560);
      else               v = ld_in(b2l, flags[9], i - 4608);
      biasv[i] = v;
    }
  }
}

// ---------------- all 4 weight transposes in one launch --------------------
__global__ __launch_bounds__(256) void transpose_all(
    const void* w1m, const void* w2m, const void* w1l, const void* w2l,
    const int* __restrict__ flags,
    u16* o1m, u16* o2m, u16* o1l, u16* o2l) {
  __shared__ u16 tile[32][33];
  const int id = blockIdx.x, which = id >> 10, t = id & 1023;
  const void* in; u16* out; int R, C, fidx;
  if (which == 0)      { in = w1m; out = o1m; R = XD; C = HD; fidx = 2; }
  else if (which == 1) { in = w2m; out = o2m; R = HD; C = YD; fidx = 4; }
  else if (which == 2) { in = w1l; out = o1l; R = XD; C = HD; fidx = 6; }
  else                 { in = w2l; out = o2l; R = HD; C = YD; fidx = 8; }
  const int f = flags[fidx];
  const int nbx = C >> 5;
  const int bx = t % nbx, by = t / nbx;
  const int c0 = bx * 32, r0 = by * 32;
  const int tx = threadIdx.x & 31, ty = threadIdx.x >> 5;
  for (int i = ty; i < 32; i += 8)
    tile[i][tx] = f2b(ld_in(in, f, (size_t)(r0 + i) * C + (c0 + tx)));
  __syncthreads();
  for (int i = ty; i < 32; i += 8)
    out[(size_t)(c0 + i) * R + (r0 + tx)] = tile[tx][i];
}

// ---------------- GEMM: BMx128 tile, BK=64, XOR-swizzled LDS, XCD swizzle --
// C[M,N] = act(A[M,K] @ Bt[N,K]^T + bias[N])
// Round-5: 1-D grid with XCD-aware decode (id&7 = XCD owns a contiguous
// M-slab, N fastest) -> per-XCD L2 footprint ~3 MB, kills the 8x cross-XCD
// fetch duplication seen in round 3/4 (FETCH 84.6 MB vs ~10 ideal).
// BM templated: 128 for GEMM1 (1024 blocks), 64 for GEMM2 (512 blocks, 2/CU
// so the barrier drain overlaps across blocks; round-4's 256 blocks = 1/CU).
// MODE 0: relu(v+bias) -> bf16 C   (GEMM1 -> h)
// MODE 1: v+bias       -> f32 C    (GEMM2 mu head)
// MODE 2: loss epilogue, no C store (GEMM2 lv head)
template <int MODE, int BM>
__global__ __launch_bounds__(256) void gemm_bt(
    const u16* __restrict__ A,      // [M,K] bf16
    const u16* __restrict__ Bt,     // [N,K] bf16
    const float* __restrict__ bias, // [N]   f32
    void* __restrict__ C, int M, int N, int K,
    const void* __restrict__ y, const int* __restrict__ flags,
    const float* __restrict__ mu, const float* __restrict__ Sy,
    const float* __restrict__ Sy2, double* __restrict__ gacc) {
  constexpr int MI = BM / 32;            // frag-rows per wave (4 @128, 2 @64)
  constexpr int AGW = BM / 32;           // A staging instrs per wave (4 / 2)
  __shared__ alignas(16) u16 As[BM * 64];
  __shared__ alignas(16) u16 Bs[128 * 64];

  const int tid  = threadIdx.x;
  const int wid  = tid >> 6;
  const int lane = tid & 63;

  // XCD-aware decode: xcd owns M-tiles [xcd*MT/8, (xcd+1)*MT/8), N fastest.
  const int MT = M / BM, NT = N / 128;
  const int id = blockIdx.x;
  const int xcd = id & 7, slot = id >> 3;
  const int bm0 = (xcd * (MT >> 3) + slot / NT) * BM;
  const int bn0 = (slot % NT) * 128;

  const int mrow = (wid >> 1) * (BM / 2);
  const int ncol = (wid & 1) * 64;
  const int quad = lane >> 4;
  const int c16  = lane & 15;
  const int cswz = c16 & 7;           // row-derived XOR key for fragment reads

  const int srow = lane >> 3;         // 0..7: row within 8-row staging group
  const int sc   = lane & 7;          // 0..7: 16-B chunk within 128-B row
  const int scg  = (sc ^ srow) * 8;   // swizzled global k element offset

  f32x4 acc[MI][4] = {};

  for (int k0 = 0; k0 < K; k0 += 64) {
#pragma unroll
    for (int j = 0; j < AGW; ++j) {   // A rows: 8 per instr
      const int grp = wid * AGW + j;
      const int row = grp * 8 + srow;
      const u16* ag = A + (size_t)(bm0 + row) * K + (k0 + scg);
      __builtin_amdgcn_global_load_lds(
          (__attribute__((address_space(1))) void*)ag,
          (__attribute__((address_space(3))) void*)(As + grp * 512), 16, 0, 0);
    }
#pragma unroll
    for (int j = 0; j < 4; ++j) {     // B rows: 128 total
      const int grp = wid * 4 + j;
      const int row = grp * 8 + srow;
      const u16* bg = Bt + (size_t)(bn0 + row) * K + (k0 + scg);
      __builtin_amdgcn_global_load_lds(
          (__attribute__((address_space(1))) void*)bg,
          (__attribute__((address_space(3))) void*)(Bs + grp * 512), 16, 0, 0);
    }
    __syncthreads();

#pragma unroll
    for (int h = 0; h < 2; ++h) {     // two K=32 MFMA steps per BK=64 tile
      const int q = h * 4 + quad;     // wanted global k-chunk
      bf16x8 af[MI], bfr[4];
#pragma unroll
      for (int mi = 0; mi < MI; ++mi) {
        const int rl = mrow + mi * 16 + c16;
        af[mi] = *(const bf16x8*)&As[rl * 64 + ((q ^ cswz) * 8)];
      }
#pragma unroll
      for (int ni = 0; ni < 4; ++ni) {
        const int rl = ncol + ni * 16 + c16;
        bfr[ni] = *(const bf16x8*)&Bs[rl * 64 + ((q ^ cswz) * 8)];
      }
#pragma unroll
      for (int mi = 0; mi < MI; ++mi)
#pragma unroll
        for (int ni = 0; ni < 4; ++ni)
          acc[mi][ni] = __builtin_amdgcn_mfma_f32_16x16x32_bf16(
              af[mi], bfr[ni], acc[mi][ni], 0, 0, 0);
    }
    __syncthreads();
  }

  // Epilogue. C/D layout (m89): col = lane&15, row = quad*4 + reg.
  if constexpr (MODE == 2) {
    const int yf = flags[1];
    const float invN = 1.0f / (float)NS;
    float s = 0.f;
#pragma unroll
    for (int ni = 0; ni < 4; ++ni) {
      const int gcol = bn0 + ncol + ni * 16 + c16;
      const float bv = bias[gcol], syv = Sy[gcol], sy2v = Sy2[gcol];
#pragma unroll
      for (int mi = 0; mi < MI; ++mi) {
#pragma unroll
        for (int r = 0; r < 4; ++r) {
          const int grow = bm0 + mrow + mi * 16 + quad * 4 + r;
          const float lvp = acc[mi][ni][r] + bv;
          const float lv = tanhf(lvp);
          const float w  = 0.5f * expf(-lv);
          const size_t ix = (size_t)grow * YD + gcol;
          const float m  = mu[ix];
          const float yv = ld_in(y, yf, ix);
          s += w * (yv * yv - 2.f * m * yv + (2.f * m * syv - sy2v) * invN);
        }
      }
    }
    for (int off = 32; off > 0; off >>= 1) s += __shfl_down(s, off);
    __shared__ double bs[4];
    if (lane == 0) bs[wid] = (double)s;
    __syncthreads();
    if (tid == 0) atomicAdd(gacc, bs[0] + bs[1] + bs[2] + bs[3]);
  } else {
#pragma unroll
    for (int ni = 0; ni < 4; ++ni) {
      const int gcol = bn0 + ncol + ni * 16 + c16;
      const float bv = bias[gcol];
#pragma unroll
      for (int mi = 0; mi < MI; ++mi) {
#pragma unroll
        for (int r = 0; r < 4; ++r) {
          const int grow = bm0 + mrow + mi * 16 + quad * 4 + r;
          float v = acc[mi][ni][r] + bv;
          if constexpr (MODE == 0)
            ((__hip_bfloat16*)C)[(size_t)grow * N + gcol] = __float2bfloat16(fmaxf(v, 0.f));
          else
            ((float*)C)[(size_t)grow * N + gcol] = v;
        }
      }
    }
  }
}

// Output is the reference's fp32 scalar (round-2 evidence) -> store float.
__global__ void finalize_kernel(const double* __restrict__ gacc,
                                float* __restrict__ out) {
  if (threadIdx.x == 0)
    out[0] = (float)(-gacc[0] / (double)NS);
}

// ---------------- launch ----------------
extern "C" void kernel_launch(void* const* d_in, const int* in_sizes, int n_in,
                              void* d_out, int out_size, void* d_ws, size_t ws_size,
                              hipStream_t stream) {
  char* ws = (char*)d_ws;
  double* gacc = (double*)ws;                    // [0,8)
  int*    flags = (int*)(ws + 16);               // [16,80)
  float*  Sy    = (float*)(ws + 128);            // 512 f32
  float*  Sy2   = (float*)(ws + 2176);           // 512 f32
  float*  biasv = (float*)(ws + 4224);           // 5120 f32 -> ends 24704
  u16* xb   = (u16*)(ws + 24704);                // [NS,XD] bf16, 8 MB
  u16* W1tm = xb + (size_t)NS * XD;              // [HD,XD] 2 MB
  u16* W2tm = W1tm + (size_t)HD * XD;            // [YD,HD] 2 MB
  u16* W1tl = W2tm + (size_t)YD * HD;            // 2 MB
  u16* W2tl = W1tl + (size_t)HD * XD;            // 2 MB
  u16* h    = W2tl + (size_t)YD * HD;            // [NS,HD] bf16, 32 MB
  float* mu = (float*)(h + (size_t)NS * HD);     // [NS,YD] f32, 16 MB (~64 MB total)

  hipMemsetAsync(d_ws, 0, 4224, stream);         // gacc + flags + Sy + Sy2

  Args10 a;
  for (int i = 0; i < 10; ++i) { a.p[i] = d_in[i]; a.n[i] = in_sizes[i]; }
  detect_kernel<<<10, 256, 0, stream>>>(a, flags);

  prep_kernel<<<2113, 256, 0, stream>>>(d_in[0], d_in[1], d_in[3], d_in[5],
                                        d_in[7], d_in[9], flags, xb, biasv, Sy, Sy2);
  transpose_all<<<4096, 256, 0, stream>>>(d_in[2], d_in[4], d_in[6], d_in[8],
                                          flags, W1tm, W2tm, W1tl, W2tl);

  const float* b1m = biasv, *b2m = biasv + 2048, *b1l = biasv + 2560, *b2l = biasv + 4608;

  // mu head: GEMM1 BM=128 (1024 blocks), GEMM2 BM=64 (512 blocks)
  gemm_bt<0, 128><<<(NS / 128) * (HD / 128), 256, 0, stream>>>(
      xb, W1tm, b1m, h, NS, HD, XD, nullptr, flags, nullptr, nullptr, nullptr, nullptr);
  gemm_bt<1, 64><<<(NS / 64) * (YD / 128), 256, 0, stream>>>(
      h, W2tm, b2m, mu, NS, YD, HD, nullptr, flags, nullptr, nullptr, nullptr, nullptr);
  // lv head (reuse h); loss fused into GEMM2 epilogue
  gemm_bt<0, 128><<<(NS / 128) * (HD / 128), 256, 0, stream>>>(
      xb, W1tl, b1l, h, NS, HD, XD, nullptr, flags, nullptr, nullptr, nullptr, nullptr);
  gemm_bt<2, 64><<<(NS / 64) * (YD / 128), 256, 0, stream>>>(
      h, W2tl, b2l, nullptr, NS, YD, HD, d_in[1], flags, mu, Sy, Sy2, gacc);

  finalize_kernel<<<1, 64, 0, stream>>>(gacc, (float*)d_out);
}